// Round 2
// 473.335 us; speedup vs baseline: 1.1335x; 1.1335x over previous
//
#include <hip/hip_runtime.h>
#include <math.h>

#define LSEQ 512
#define DG 256
#define DB 128
#define NH 8
#define HD 32
#define EPSV 1e-5f
#define LP2 516          // attn logits LDS row stride

typedef __attribute__((ext_vector_type(8))) short bf16x8;
typedef __attribute__((ext_vector_type(4))) float f32x4;

__device__ __forceinline__ unsigned short f2bf(float x) {
    unsigned int u = __float_as_uint(x);
    u += 0x7FFFu + ((u >> 16) & 1u);       // RNE
    return (unsigned short)(u >> 16);
}
__device__ __forceinline__ float bf2f(unsigned short h) {
    return __uint_as_float(((unsigned int)h) << 16);
}

// ---------------------------------------------------------------------------
// Kernel 1 (fused): blocks 0..255 do layernorm(x)+Q/K/V/Gate projections
// (latency-bound, hides under the HBM stream); blocks 256..1279 do bias
// layernorm + @Wb -> pair_ws (THE HBM streamer, unchanged inner loop).
// ---------------------------------------------------------------------------
__global__ __launch_bounds__(256) void prep_pairb_kernel(
    const float* __restrict__ x, const float* __restrict__ g_gamma,
    const float* __restrict__ g_beta, const float* __restrict__ Wq,
    const float* __restrict__ Wk, const float* __restrict__ Wv,
    const float* __restrict__ Wg, const float* __restrict__ bg,
    float* __restrict__ q_ws, float* __restrict__ k_ws,
    float* __restrict__ v_ws, float* __restrict__ g_ws,
    const float* __restrict__ bias, const float* __restrict__ b_gamma,
    const float* __restrict__ b_beta, const float* __restrict__ Wb,
    float* __restrict__ pair_ws)
{
    __shared__ float lds[4 * 2 * 2048];      // 64 KB, shared by both roles
    const int t = threadIdx.x;

    if (blockIdx.x < 256) {
        // ---------------- prep role ----------------
        float (*xs)[DG] = (float(*)[DG])lds;     // first 4 KB
        const int wave = t >> 6, lane = t & 63;
        const int row0 = blockIdx.x << 2;

        {   // one wave per row: layernorm over 256
            const int row = row0 + wave;
            const float4 xv = *(const float4*)(x + (size_t)row * DG + lane * 4);
            float s  = xv.x + xv.y + xv.z + xv.w;
            float ss = xv.x*xv.x + xv.y*xv.y + xv.z*xv.z + xv.w*xv.w;
            #pragma unroll
            for (int m = 32; m >= 1; m >>= 1) { s += __shfl_xor(s, m); ss += __shfl_xor(ss, m); }
            const float mean = s * (1.f / DG);
            const float rstd = rsqrtf(ss * (1.f / DG) - mean * mean + EPSV);
            const float4 gg = *(const float4*)(g_gamma + lane * 4);
            const float4 gb = *(const float4*)(g_beta + lane * 4);
            float4 xo;
            xo.x = (xv.x - mean) * rstd * gg.x + gb.x;
            xo.y = (xv.y - mean) * rstd * gg.y + gb.y;
            xo.z = (xv.z - mean) * rstd * gg.z + gb.z;
            xo.w = (xv.w - mean) * rstd * gg.w + gb.w;
            *(float4*)&xs[wave][lane * 4] = xo;
        }
        __syncthreads();

        float aq[4] = {0,0,0,0}, ak[4] = {0,0,0,0}, av[4] = {0,0,0,0}, ag[4] = {0,0,0,0};
        #pragma unroll 4
        for (int c = 0; c < DG; ++c) {
            const float wq = Wq[(size_t)c * DG + t];
            const float wk = Wk[(size_t)c * DG + t];
            const float wv = Wv[(size_t)c * DG + t];
            const float wg = Wg[(size_t)c * DG + t];
            #pragma unroll
            for (int r = 0; r < 4; ++r) {
                const float xr = xs[r][c];
                aq[r] = fmaf(xr, wq, aq[r]);
                ak[r] = fmaf(xr, wk, ak[r]);
                av[r] = fmaf(xr, wv, av[r]);
                ag[r] = fmaf(xr, wg, ag[r]);
            }
        }

        const float scal = 0.17677669529663687f;  // 1/sqrt(32)
        const float bgv = bg[t];
        #pragma unroll
        for (int r = 0; r < 4; ++r) {
            const size_t o = (size_t)(row0 + r) * DG + t;
            q_ws[o] = aq[r];
            k_ws[o] = ak[r] * scal;
            v_ws[o] = av[r];
            g_ws[o] = 1.f / (1.f + __expf(-(ag[r] + bgv)));
        }
        return;
    }

    // ---------------- pairb role ----------------
    const int w = t >> 6, l = t & 63;
    const int n = l & 15, quad = l >> 4;
    const int bq = blockIdx.x - 256;

    // B-fragments (constant across all tiles): gw = gamma*Wb, split hi/lo.
    // col n==8 of gwhi = 1.0 -> MFMA also produces row sums in acc at n=8.
    bf16x8 gwhi[4], gwlo[4];
    float S1 = 0.f, S0 = 0.f;
    #pragma unroll
    for (int ks = 0; ks < 4; ++ks) {
        #pragma unroll
        for (int j = 0; j < 8; ++j) {
            const int c = ks * 32 + quad * 8 + j;
            const float wb = (n < 8) ? Wb[c * 8 + n] : 0.f;
            const float wv = b_gamma[c] * wb;
            S1 += wv;
            S0 += b_beta[c] * wb;
            unsigned short hi = f2bf(wv);
            unsigned short lo = f2bf(wv - bf2f(hi));
            if (n == 8) { hi = 0x3F80; lo = 0; }   // ones column
            gwhi[ks][j] = (short)hi;
            gwlo[ks][j] = (short)lo;
        }
    }
    S1 += __shfl_xor(S1, 16); S1 += __shfl_xor(S1, 32);
    S0 += __shfl_xor(S0, 16); S0 += __shfl_xor(S0, 32);

    float* myl = lds + w * 4096;                       // my 2 buffers
    const size_t rowbase = (size_t)bq * LSEQ + w * 16; // this wave's rows

    auto stage = [&](int tt, int buf) {
        const float* src = bias + (rowbase + (size_t)tt * 64) * DB;
        float* dst = myl + buf * 2048;
        #pragma unroll
        for (int i = 0; i < 8; ++i) {
            __builtin_amdgcn_global_load_lds(
                (const __attribute__((address_space(1))) void*)(src + i * 256 + l * 4),
                (__attribute__((address_space(3))) void*)(dst + i * 256 + l * 4),
                16, 0, 0);
        }
    };

    auto compute = [&](int tt, int buf) {
        const float* d = myl + buf * 2048 + n * 128 + quad * 8;
        f32x4 acc = {0.f, 0.f, 0.f, 0.f};
        float ssq = 0.f;
        #pragma unroll
        for (int ks = 0; ks < 4; ++ks) {
            const float4 x0 = *(const float4*)(d + ks * 32);
            const float4 x1 = *(const float4*)(d + ks * 32 + 4);
            ssq = fmaf(x0.x,x0.x, fmaf(x0.y,x0.y, fmaf(x0.z,x0.z, fmaf(x0.w,x0.w, ssq))));
            ssq = fmaf(x1.x,x1.x, fmaf(x1.y,x1.y, fmaf(x1.z,x1.z, fmaf(x1.w,x1.w, ssq))));
            const float xsv[8] = {x0.x,x0.y,x0.z,x0.w,x1.x,x1.y,x1.z,x1.w};
            bf16x8 ahi, alo;
            #pragma unroll
            for (int j = 0; j < 8; ++j) {
                const unsigned short hi = f2bf(xsv[j]);
                ahi[j] = (short)hi;
                alo[j] = (short)f2bf(xsv[j] - bf2f(hi));
            }
            acc = __builtin_amdgcn_mfma_f32_16x16x32_bf16(ahi, gwhi[ks], acc, 0, 0, 0);
            acc = __builtin_amdgcn_mfma_f32_16x16x32_bf16(alo, gwhi[ks], acc, 0, 0, 0);
            acc = __builtin_amdgcn_mfma_f32_16x16x32_bf16(ahi, gwlo[ks], acc, 0, 0, 0);
        }
        ssq += __shfl_xor(ssq, 16);
        ssq += __shfl_xor(ssq, 32);
        // D layout: row=(quad*4+reg), col=n. Row sums live at lane quad*16+8.
        float* pout = pair_ws + (rowbase + (size_t)tt * 64 + quad * 4) * NH + n;
        #pragma unroll
        for (int reg = 0; reg < 4; ++reg) {
            const float sumr = __uint_as_float((unsigned)__builtin_amdgcn_ds_bpermute(
                (quad * 16 + 8) * 4, (int)__float_as_uint(acc[reg])));
            const float ssqr = __uint_as_float((unsigned)__builtin_amdgcn_ds_bpermute(
                (quad * 4 + reg) * 4, (int)__float_as_uint(ssq)));
            const float mean = sumr * (1.f / DB);
            const float var  = ssqr * (1.f / DB) - mean * mean;
            const float rstd = rsqrtf(var + EPSV);
            const float p = rstd * (acc[reg] - mean * S1) + S0;
            if (n < NH) pout[reg * NH] = p;
        }
    };

    stage(0, 0);
    stage(1, 1);
    asm volatile("s_waitcnt vmcnt(8)" ::: "memory");
    compute(0, 0);
    for (int tt = 1; tt < 7; ++tt) {
        stage(tt + 1, (tt + 1) & 1);
        asm volatile("s_waitcnt vmcnt(12)" ::: "memory");   // 8 new loads + 4 stores
        compute(tt, tt & 1);
    }
    asm volatile("s_waitcnt vmcnt(4)" ::: "memory");
    compute(7, 1);
}

// ---------------------------------------------------------------------------
// Kernel 2: attention. 512 blocks (2 q-rows each) x 512 thr.
// logits(+pair) in LDS -> softmax -> @v -> gate -> @Wout.
// Phase 1 coalesced: wave=h, lanes=(d4,r) -> every load instruction
// covers 8 fully-used 128B lines; dot finished with 3 shfl_xor stages.
// ---------------------------------------------------------------------------
__global__ __launch_bounds__(512) void attn_kernel(
    const float* __restrict__ pair_ws, const float* __restrict__ Wout,
    const float* __restrict__ bout, const float* __restrict__ q_ws,
    const float* __restrict__ k_ws, const float* __restrict__ v_ws,
    const float* __restrict__ g_ws, float* __restrict__ out)
{
    __shared__ float lg[2 * NH * LP2];     // 33 KB logits [q][h][k]
    __shared__ float q_s[2 * DG];
    __shared__ float ps[4 * 2 * 64 * 4];   // PV partials [s][q][c4]f4, 8 KB
    __shared__ float row_s[2 * DG];
    __shared__ float rden[16];

    const int t = threadIdx.x;
    const int b = blockIdx.x >> 8;
    const int q0 = (blockIdx.x & 255) * 2;

    // ---- Phase 0: stage pair -> lg (transposed), q rows ----
    {
        const float* pbase = pair_ws + ((size_t)(b * LSEQ + q0)) * LSEQ * NH;
        #pragma unroll
        for (int r = 0; r < 4; ++r) {
            const int f = r * 512 + t;            // float4 index in 2 q slices
            const float4 pv = *(const float4*)(pbase + (size_t)f * 4);
            const int q = f >> 10;
            const int o = (f * 4) & 4095;
            const int k = o >> 3, hb = o & 7;     // hb in {0,4}
            float* dst = lg + (q * NH + hb) * LP2 + k;
            dst[0] = pv.x; dst[LP2] = pv.y; dst[2*LP2] = pv.z; dst[3*LP2] = pv.w;
        }
        q_s[t] = q_ws[((size_t)(b * LSEQ + q0)) * DG + t];
    }
    __syncthreads();

    // ---- Phase 1: lg += q . k  (coalesced: 8 rows x 128B h-slice / instr) ----
    {
        const int h = t >> 6;                 // wave = head
        const int lane = t & 63;
        const int d4 = lane >> 3, r = lane & 7;
        const float4 qa = *(const float4*)(q_s + h * HD + d4 * 4);
        const float4 qb = *(const float4*)(q_s + DG + h * HD + d4 * 4);
        const float* kbase = k_ws + ((size_t)(b * LSEQ)) * DG + h * HD + d4 * 4;
        float* l0 = lg + (0 * NH + h) * LP2;
        float* l1 = lg + (1 * NH + h) * LP2;
        #pragma unroll 4
        for (int kb8 = 0; kb8 < 64; ++kb8) {
            const int krow = kb8 * 8 + r;
            const float4 kv = *(const float4*)(kbase + (size_t)krow * DG);
            float a0 = fmaf(kv.x, qa.x, fmaf(kv.y, qa.y, fmaf(kv.z, qa.z, kv.w * qa.w)));
            float a1 = fmaf(kv.x, qb.x, fmaf(kv.y, qb.y, fmaf(kv.z, qb.z, kv.w * qb.w)));
            a0 += __shfl_xor(a0, 8);  a1 += __shfl_xor(a1, 8);
            a0 += __shfl_xor(a0, 16); a1 += __shfl_xor(a1, 16);
            a0 += __shfl_xor(a0, 32); a1 += __shfl_xor(a1, 32);
            if (d4 == 0) { l0[krow] += a0; l1[krow] += a1; }
        }
    }
    __syncthreads();

    // ---- Phase 2: softmax over k per (q,h): 32 lanes per combo ----
    {
        const int qh = t >> 5, l32 = t & 31;
        float* lrow = lg + qh * LP2;
        float mx = -1e30f;
        #pragma unroll
        for (int i = 0; i < 16; ++i) mx = fmaxf(mx, lrow[l32 + i * 32]);
        #pragma unroll
        for (int m = 16; m >= 1; m >>= 1) mx = fmaxf(mx, __shfl_xor(mx, m));
        float s = 0.f;
        #pragma unroll
        for (int i = 0; i < 16; ++i) {
            const int k = l32 + i * 32;
            const float e = __expf(lrow[k] - mx);
            lrow[k] = e;
            s += e;
        }
        #pragma unroll
        for (int m = 16; m >= 1; m >>= 1) s += __shfl_xor(s, m);
        if (l32 == 0) rden[qh] = 1.f / s;
    }
    __syncthreads();

    // ---- Phase 3: PV, k split 4 ways ----
    {
        const int q = t >> 8, s4 = (t >> 6) & 3, c4 = t & 63;
        const int h = c4 >> 3;
        const float* vb = v_ws + ((size_t)(b * LSEQ + s4 * 128)) * DG + c4 * 4;
        const float* prow = lg + (q * NH + h) * LP2 + s4 * 128;
        float4 a = {0.f, 0.f, 0.f, 0.f};
        #pragma unroll 4
        for (int i = 0; i < 128; ++i) {
            const float p = prow[i];
            const float4 vv = *(const float4*)(vb + (size_t)i * DG);
            a.x = fmaf(p, vv.x, a.x);
            a.y = fmaf(p, vv.y, a.y);
            a.z = fmaf(p, vv.z, a.z);
            a.w = fmaf(p, vv.w, a.w);
        }
        *(float4*)&ps[((s4 * 2 + q) * 64 + c4) * 4] = a;
    }
    __syncthreads();
    if (t < 128) {
        const int q = t >> 6, c4 = t & 63, h = c4 >> 3;
        float4 a = *(const float4*)&ps[((0 * 2 + q) * 64 + c4) * 4];
        #pragma unroll
        for (int s4 = 1; s4 < 4; ++s4) {
            const float4 p4 = *(const float4*)&ps[((s4 * 2 + q) * 64 + c4) * 4];
            a.x += p4.x; a.y += p4.y; a.z += p4.z; a.w += p4.w;
        }
        const float sc = rden[q * NH + h];
        const float4 g4 = *(const float4*)(g_ws + ((size_t)(b * LSEQ + q0 + q)) * DG + c4 * 4);
        float* rs = row_s + q * DG + c4 * 4;
        rs[0] = a.x * sc * g4.x;
        rs[1] = a.y * sc * g4.y;
        rs[2] = a.z * sc * g4.z;
        rs[3] = a.w * sc * g4.w;
    }
    __syncthreads();

    // ---- Phase 4: row_s @ Wout + bout ----
    {
        const int q = t >> 8, co = t & 255;
        const float* rs = row_s + q * DG;
        const float* wo = Wout + co;
        float a = 0.f;
        #pragma unroll 4
        for (int c = 0; c < DG; ++c)
            a = fmaf(rs[c], wo[(size_t)c * DG], a);
        out[((size_t)(b * LSEQ + q0 + q)) * DG + co] = a + bout[co];
    }
}

extern "C" void kernel_launch(void* const* d_in, const int* in_sizes, int n_in,
                              void* d_out, int out_size, void* d_ws, size_t ws_size,
                              hipStream_t stream)
{
    const float* x       = (const float*)d_in[0];
    const float* bias    = (const float*)d_in[1];
    const float* g_gamma = (const float*)d_in[2];
    const float* g_beta  = (const float*)d_in[3];
    const float* b_gamma = (const float*)d_in[4];
    const float* b_beta  = (const float*)d_in[5];
    const float* Wq      = (const float*)d_in[6];
    const float* Wk      = (const float*)d_in[7];
    const float* Wv      = (const float*)d_in[8];
    const float* Wb      = (const float*)d_in[9];
    const float* Wg      = (const float*)d_in[10];
    const float* bg      = (const float*)d_in[11];
    const float* Wout    = (const float*)d_in[12];
    const float* bout    = (const float*)d_in[13];
    float* out = (float*)d_out;

    float* ws      = (float*)d_ws;
    float* q_ws    = ws;                    // 1 MB each
    float* k_ws    = ws + 262144;
    float* v_ws    = ws + 2 * 262144;
    float* g_ws    = ws + 3 * 262144;
    float* pair_ws = ws + 4 * 262144;       // [1024*512*8] = 16 MB

    hipLaunchKernelGGL(prep_pairb_kernel, dim3(1280), dim3(256), 0, stream,
                       x, g_gamma, g_beta, Wq, Wk, Wv, Wg, bg,
                       q_ws, k_ws, v_ws, g_ws,
                       bias, b_gamma, b_beta, Wb, pair_ws);
    hipLaunchKernelGGL(attn_kernel, dim3(512), dim3(512), 0, stream,
                       pair_ws, Wout, bout, q_ws, k_ws, v_ws, g_ws, out);
}